// Round 12
// baseline (164.252 us; speedup 1.0000x reference)
//
#include <hip/hip_runtime.h>
#include <float.h>

// Problem constants (fixed by reference: B=8, D=64, H=64, W=64, K=8192)
constexpr int KCODES = 8192;
constexpr int DDIM   = 64;
constexpr int NTOK   = 32768;
constexpr int MT     = 64;                 // tokens per WG (4 sets x 16)
constexpr int NSETS  = MT / 16;            // 4
constexpr int KC     = 64;                 // codes per chunk
constexpr int NCH    = KCODES / KC;        // 128 chunks
constexpr int CHPW   = NCH / 2;            // 64 chunks per wave (chunk-split)
constexpr int CBCHUNK = KC * DDIM * 2;     // 8192 B (64 codes x 64 d x bf16, hi only)

constexpr int RQ    = 3;                   // LDS staging ring depth (per wave)
constexpr int ASLOT = 2304;                // 2 KB A-frags + 256 B hn block
constexpr int NCELL = 32;                  // 8 waves x 4 quads

typedef short v8s __attribute__((ext_vector_type(8)));
typedef float v4f __attribute__((ext_vector_type(4)));

static __device__ __forceinline__ unsigned short f2bf(float f) {
  union { float f; unsigned u; } v; v.f = f;
  return (unsigned short)((v.u + 0x7fffu + ((v.u >> 16) & 1u)) >> 16);  // RNE
}

// async global->LDS DMA: dest = wave-uniform LDS base + lane*size (m104);
// source is per-lane. Tracked by vmcnt.
static __device__ __forceinline__ void dma16(const void* g, void* l) {
  __builtin_amdgcn_global_load_lds(
      (const __attribute__((address_space(1))) void*)g,
      (__attribute__((address_space(3))) void*)l, 16, 0, 0);
}
static __device__ __forceinline__ void dma4(const void* g, void* l) {
  __builtin_amdgcn_global_load_lds(
      (const __attribute__((address_space(1))) void*)g,
      (__attribute__((address_space(3))) void*)l, 4, 0, 0);
}

// ---- fused prep: bf16 hi codebook, FRAGMENT-LINEAR for mfma_16x16x32_bf16
// A-operand (A[m=lane&15][k=(lane>>4)*8+j]), + biased half-norms
// hn[k] = 0.5*||c_k||^2 + 2.0 (bias keeps phase-1 scores positive -> fp32
// bit pattern monotone for the packed-key argmin; scores land in [~0.7,~4.5]).
// Per chunk c: byte off = c*8192 + g*2048 + ks*1024 + lane*16 + j*2.
// Grid 256 x 128 threads (2 blocks per chunk): full-device fill.
__global__ __launch_bounds__(128) void prep_kernel(
    const float* __restrict__ cb, unsigned short* __restrict__ wcb,
    float* __restrict__ hn) {
  const int c = blockIdx.x >> 1;            // chunk 0..127
  const int tid = threadIdx.x;
  const int g = ((blockIdx.x & 1) << 1) | (tid >> 6);   // 16-code group 0..3
  const int lane = tid & 63;
  const int quad = lane >> 4, col = lane & 15;
  const int code = c * KC + g * 16 + col;
  const float* src = cb + (size_t)code * DDIM;
  float sq = 0.f;
#pragma unroll
  for (int ks = 0; ks < 2; ++ks) {
    v8s hi;
#pragma unroll
    for (int j = 0; j < 8; ++j) {
      const float x = src[ks * 32 + quad * 8 + j];
      sq += x * x;
      hi[j] = (short)f2bf(x);
    }
    const size_t b0 = ((size_t)c * CBCHUNK + g * 2048 + ks * 1024 + lane * 16) / 2;
    *reinterpret_cast<v8s*>(wcb + b0) = hi;
  }
  sq += __shfl_xor(sq, 16);
  sq += __shfl_xor(sq, 32);
  if (quad == 0) hn[code] = 0.5f * sq + 2.0f;
}

// Phase 1 (SCREEN): hi-only bf16 MFMA, score ~= hn - xh.ch.
//   Screening error e = xl.c + xh.cl: RMS ~2.5e-4, |e| <= ~2.8e-3 at 11
//   sigma. 512-thread WG, MT=64, CHUNK-SPLIT: waves 0-3 screen chunks
//   0..63 (row-slice wr=wv&3), waves 4-7 chunks 64..127 -> 8 MFMAs per
//   wave-chunk (R3 amortization) at 16 waves/CU (2 WG x 8 waves, 4
//   waves/SIMD). This is R5/R7's geometry WITHOUT the VGPR spill: HIP
//   __launch_bounds__ 2nd arg is min BLOCKS/CU (CUDA semantics) — R5's
//   (512,4) requested 32 waves/CU -> VGPR cap 64 -> scratch thrash
//   (VGPR=64 + inflated FETCH in R5/R7 counters). (512,2) caps at 128.
//   Per-wave LDS ring depth 3 (2x dma16 A + 1x dma4 hn per chunk,
//   counted s_waitcnt vmcnt(6), no in-loop barriers; each wave stages
//   and reads only its own slice). Clean-run service rates: 16 waves/CU
//   = 44-45 ns/wave-iter (R0/R2) vs 8 waves = 54 (R3) -> predicted loop
//   ~46 us vs 55. Branchless packed-key top-2 per (lane,set) cell:
//   key = (score-bits & ~511) | (itl*4 + r), itl<64 fits 9 bits; floor
//   quantization <= 512 ulp <= 2.4e-4.
// Phase 2 (R11's candidate-parallel epilogue, widened to 64 slots):
//   (A) wave 0: per-token smin/cnt/fidx scan over 32 cells (verbatim
//       semantics); cnt==1 -> widx; else push token to LDS worklist.
//   (B) one refine token per WAVE (8 concurrent), ONE candidate slot
//       (c,h) per lane (64 slots = 64 lanes); each lane computes the
//       numpy-fp32-faithful Dv once (pairwise-8 sums, D=fl(fl(S-2p)+N),
//       correctly-rounded-fp64 p); width-64 lexicographic (Dv,idx)
//       shuffle-reduce == serial loop's tie-break (lexicographic min is
//       associative; candidate codes are pairwise distinct).
//   Fast path proof (unchanged): for any candidate with stored > lim:
//   true > stored - e > smin + 8e-3 - 2.8e-3; smin >= true_min - e -
//   2.4e-4 -> true - true_min > 2e-3 >> numpy ulp noise -> numpy cannot
//   prefer it; a distinct numpy-winner is itself within lim -> cnt >= 2
//   -> refine. Ties at smin give cnt >= 2, so fast-path fidx is unique.
__global__ __launch_bounds__(512, 2) void vq_kernel(
    const float* __restrict__ ze, const float* __restrict__ cb,
    const float* __restrict__ hn, const unsigned short* __restrict__ wcb,
    float* __restrict__ out) {
  // LDS: per-wave staging ring; wave wv owns [wv*RQ*ASLOT, +RQ*ASLOT).
  // Epilogue arrays (17.2 KB) alias the ring after drain + barrier.
  __shared__ __align__(16) char smem[8 * RQ * ASLOT];   // 55296 B

  const int tid = threadIdx.x, lane = tid & 63, wv = tid >> 6;
  const int col = lane & 15, quad = lane >> 4;
  const int wr = wv & 3;              // code row-slice (16 codes of each chunk)
  const int c0 = (wv >> 2) * CHPW;    // first chunk of this wave's half
  const int t0 = blockIdx.x * MT;
  const int bb = t0 >> 12, hw0 = t0 & 4095;   // 4096 % 64 == 0: one batch per WG
  const float* zb = ze + (size_t)bb * (DDIM * 4096) + hw0;

  // ---- B-frags: 4 sets x 16 tokens, negated bf16-hi, in registers.
  // B[k=(lane>>4)*8+j][n=lane&15]; token = s*16 + col; d = ks*32 + quad*8 + j.
  v8s nxh[NSETS][2];
#pragma unroll
  for (int s = 0; s < NSETS; ++s) {
    const int mtok = s * 16 + col;
#pragma unroll
    for (int ks = 0; ks < 2; ++ks) {
#pragma unroll
      for (int j = 0; j < 8; ++j) {
        const int d = ks * 32 + quad * 8 + j;
        nxh[s][ks][j] = (short)f2bf(-zb[(size_t)d * 4096 + mtok]);
      }
    }
  }

  char* wbase = smem + wv * (RQ * ASLOT);
  const char* wsrc = (const char*)wcb + wr * 2048 + lane * 16;
  const int hoff = 2048 + wr * 64 + quad * 16;   // this cell's hv within a slot

  // Stage global chunk gc -> slot: 2x 16B A DMAs (2 KB) + 1x 4B hn DMA (256 B).
  auto stage = [&](int gc, int slot) {
    const char* src = wsrc + (size_t)gc * CBCHUNK;
    char* dst = wbase + slot * ASLOT;
    dma16(src, dst);
    dma16(src + 1024, dst + 1024);
    dma4((const char*)(hn + gc * KC) + lane * 4, dst + 2048);
  };

  unsigned m1[NSETS] = {0xFFFFFFFFu, 0xFFFFFFFFu, 0xFFFFFFFFu, 0xFFFFFFFFu};
  unsigned m2[NSETS] = {0xFFFFFFFFu, 0xFFFFFFFFu, 0xFFFFFFFFu, 0xFFFFFFFFu};

  auto compute = [&](const v8s (&A)[2], const v4f hv, int itl) {
    const unsigned base9 = (unsigned)(itl * 4);   // 9-bit cell-local index base
#pragma unroll
    for (int s = 0; s < NSETS; ++s) {             // 4 independent MFMA chains
      v4f acc = __builtin_amdgcn_mfma_f32_16x16x32_bf16(A[0], nxh[s][0], hv, 0, 0, 0);
      acc = __builtin_amdgcn_mfma_f32_16x16x32_bf16(A[1], nxh[s][1], acc, 0, 0, 0);
      unsigned k0 = (__float_as_uint(acc[0]) & ~511u) | (base9 + 0);
      unsigned k1 = (__float_as_uint(acc[1]) & ~511u) | (base9 + 1);
      unsigned k2 = (__float_as_uint(acc[2]) & ~511u) | (base9 + 2);
      unsigned k3 = (__float_as_uint(acc[3]) & ~511u) | (base9 + 3);
      const unsigned km = min(min(k0, k1), min(k2, k3));
      const unsigned old1 = m1[s];
      m1[s] = min(old1, km);
      m2[s] = min(m2[s], max(old1, km));   // branchless 2nd-best
    }
  };

  // ---- airtight vmcnt ledger: drain prologue loads before first stage.
  asm volatile("s_waitcnt vmcnt(0)" ::: "memory");
  __builtin_amdgcn_sched_barrier(0);

#pragma unroll
  for (int r = 0; r < RQ; ++r) stage(c0 + r, r);   // 9 DMAs in flight

  int sl = 0;
  for (int itl = 0; itl < CHPW; ++itl) {
    // Chunk itl's 3 DMAs landed once <= 6 remain outstanding (in-order).
    asm volatile("s_waitcnt vmcnt(6)" ::: "memory");
    __builtin_amdgcn_sched_barrier(0);

    v8s A[2]; v4f hv;
    {
      const char* b = wbase + sl * ASLOT;
      A[0] = *reinterpret_cast<const v8s*>(b + lane * 16);
      A[1] = *reinterpret_cast<const v8s*>(b + 1024 + lane * 16);
      hv   = *reinterpret_cast<const v4f*>(b + hoff);
    }
    compute(A, hv, itl);

    // ds_reads of this slot fully retired before the DMA overwrite lands.
    asm volatile("s_waitcnt lgkmcnt(0)" ::: "memory");
    __builtin_amdgcn_sched_barrier(0);
    stage(c0 + ((itl + RQ) & (CHPW - 1)), sl);   // tail wrap: never read
    sl = (sl == RQ - 1) ? 0 : sl + 1;
  }

  // Drain in-flight DMAs, then all waves quiesce before aliasing LDS.
  asm volatile("s_waitcnt vmcnt(0)" ::: "memory");
  __syncthreads();

  unsigned (*c_k1)[MT] = (unsigned (*)[MT])(smem);          // 8 KB
  unsigned (*c_k2)[MT] = (unsigned (*)[MT])(smem + 8192);   // 8 KB
  int*   widx  = (int*)(smem + 16384);                      // 256 B
  float* limv  = (float*)(smem + 16640);                    // 256 B
  int*   rlist = (int*)(smem + 16896);                      // 256 B
  int*   rcnt  = (int*)(smem + 17152);                      // 4 B

  // ---- surface per-cell top-2 keys (cell = wv*4+quad; 32 cells x 256 codes)
  {
    const int cell = wv * 4 + quad;
#pragma unroll
    for (int s = 0; s < NSETS; ++s) {
      const int m = s * 16 + col;
      c_k1[cell][m] = m1[s];
      c_k2[cell][m] = m2[s];
    }
  }
  if (tid == 0) *rcnt = 0;
  __syncthreads();

  // decode: cell c, key K -> code = ((c>>4)*64 + localIt)*64 + row bits
  auto decode = [](int c, unsigned K) {
    return ((c >> 4) * CHPW + (int)((K & 511u) >> 2)) * KC +
           ((c >> 2) & 3) * 16 + (c & 3) * 4 + (int)(K & 3u);
  };

  // ---- step A: wave 0 scans per-token smin/cnt; fast path or worklist ----
  if (tid < MT) {
    const int m = tid;
    float smin = FLT_MAX; int fidx = 0x7fffffff;
#pragma unroll
    for (int c = 0; c < NCELL; ++c) {
      const unsigned Kc = c_k1[c][m];
      const float a = __uint_as_float(Kc & ~511u);
      if (a < smin) { smin = a; fidx = decode(c, Kc); }
    }
    const float lim = smin + 8e-3f;   // covers 2*e_screen(2.8e-3) + key floor
                                      // 2.4e-4 + numpy noise, ~1.4x slack
    int cnt = 0;
#pragma unroll
    for (int c = 0; c < NCELL; ++c) {
      cnt += (__uint_as_float(c_k1[c][m] & ~511u) <= lim);
      cnt += (__uint_as_float(c_k2[c][m] & ~511u) <= lim);
    }
    if (cnt == 1) {
      widx[m] = fidx;   // unique in-margin candidate == numpy argmin
    } else {
      limv[m] = lim;
      const int pos = atomicAdd(rcnt, 1);
      rlist[pos] = m;
    }
  }
  __syncthreads();

  // ---- step B: candidate-parallel refine: one token per WAVE, one
  // candidate slot (c,h) per lane, lexicographic (Dv,idx) reduce ----
  {
    const int nref = *rcnt;
    for (int i = wv; i < nref; i += 8) {
#pragma clang fp contract(off)   // numpy: separate mul then add; no FMA
      const int m = rlist[i];
      const float lim = limv[m];
      const int c = lane >> 1, h = lane & 1;
      const unsigned Kc = h ? c_k2[c][m] : c_k1[c][m];
      const float sp = __uint_as_float(Kc & ~511u);

      const float* xz = zb + m;   // per-token column of ze (L2-hot broadcast)

      float r[8];
      for (int j = 0; j < 8; ++j) { const float v = xz[(size_t)j * 4096]; r[j] = v * v; }
      for (int q = 8; q < DDIM; q += 8)
        for (int j = 0; j < 8; ++j) { const float v = xz[(size_t)(q + j) * 4096]; r[j] += v * v; }
      const float S = ((r[0] + r[1]) + (r[2] + r[3])) + ((r[4] + r[5]) + (r[6] + r[7]));

      float Dv = FLT_MAX;
      int idx = 0x7fffffff;
      if (sp <= lim) {
        idx = decode(c, Kc);
        const float* crow = cb + (size_t)idx * DDIM;
        float rn[8];
        for (int j = 0; j < 8; ++j) rn[j] = crow[j] * crow[j];
        for (int q = 8; q < DDIM; q += 8)
          for (int j = 0; j < 8; ++j) rn[j] += crow[q + j] * crow[q + j];
        const float Nk =
            ((rn[0] + rn[1]) + (rn[2] + rn[3])) + ((rn[4] + rn[5]) + (rn[6] + rn[7]));

        double p64 = 0.0;
        for (int d = 0; d < DDIM; ++d)
          p64 += (double)xz[(size_t)d * 4096] * (double)crow[d];
        const float pf = (float)p64;

        const float twop = 2.0f * pf;
        const float t1   = S - twop;
        Dv = t1 + Nk;
      }
#pragma unroll
      for (int off = 1; off < 64; off <<= 1) {
        const float oD = __shfl_xor(Dv, off);
        const int   oI = __shfl_xor(idx, off);
        if (oD < Dv || (oD == Dv && oI < idx)) { Dv = oD; idx = oI; }
      }
      if (lane == 0) widx[m] = idx;
    }
  }
  __syncthreads();

  // ---- step C: gather winners, write z_q (64-lane coalesced rows) ----
  {
    const int m = tid & 63, dg = tid >> 6;    // dg 0..7
    const int wi = widx[m];
    const float* crow = cb + (size_t)wi * DDIM;
    float* ob = out + (size_t)bb * (DDIM * 4096) + hw0;
#pragma unroll
    for (int p = 0; p < 8; ++p) {
      const int d = dg * 8 + p;
      ob[(size_t)d * 4096 + m] = crow[d];
    }
  }
}

extern "C" void kernel_launch(void* const* d_in, const int* in_sizes, int n_in,
                              void* d_out, int out_size, void* d_ws, size_t ws_size,
                              hipStream_t stream) {
  const float* ze = (const float*)d_in[0];    // [8,64,64,64]
  const float* cb = (const float*)d_in[1];    // [8192,64]
  float* hn = (float*)d_ws;                                     // 32 KB
  unsigned short* wcb = (unsigned short*)((char*)d_ws + 32768); // 1 MB frag-linear hi
  float* out = (float*)d_out;

  prep_kernel<<<256, 128, 0, stream>>>(cb, wcb, hn);
  vq_kernel<<<NTOK / MT, 512, 0, stream>>>(ze, cb, hn, wcb, out);
}